// Round 3
// baseline (384.675 us; speedup 1.0000x reference)
//
#include <hip/hip_runtime.h>
#include <cstdint>
#include <cstddef>

// SOM BMU: dists[b,m] = ||x[b] - W[:,m] + eps||, argmin/min over m.
//   sq = rowTerm[b] + colTerm[m] - 2*dot(x[b],W[:,m]) + D*eps^2
// dot via split-precision f16 MFMA (xh.wh + xh.wl + xl.wh, ~2^-22 rel err).
// 32x32x16 MFMA, XOR-swizzled LDS staging (conflict-free ds_read_b128).
// Argmin via packed u64 key (dist_bits<<32 | m) + atomicMin.

#define B_  2048
#define D_  1024
#define M_  16384
#define EPS_ 1e-6f

typedef _Float16 v8h  __attribute__((ext_vector_type(8)));
typedef _Float16 v4h  __attribute__((ext_vector_type(4)));
typedef float    v4f  __attribute__((ext_vector_type(4)));
typedef float    v16f __attribute__((ext_vector_type(16)));

static __device__ __forceinline__ unsigned long long umin64(unsigned long long a,
                                                            unsigned long long b) {
    return a < b ? a : b;
}

#define GLDS16(g, l)                                                            \
    __builtin_amdgcn_global_load_lds(                                           \
        (const __attribute__((address_space(1))) void*)(g),                     \
        (__attribute__((address_space(3))) void*)(l), 16, 0, 0)

// ---------- convert x -> xh,xl (f16) + rowTerm ----------
__global__ void xconv(const float* __restrict__ x,
                      _Float16* __restrict__ xh, _Float16* __restrict__ xl,
                      float* __restrict__ rowTerm) {
    int b = blockIdx.x;
    int t = threadIdx.x;  // 256
    const float4 v = *(const float4*)(x + (size_t)b * D_ + t * 4);
    v4h h, l;
    float acc = 0.f;
    float vv[4] = {v.x, v.y, v.z, v.w};
    #pragma unroll
    for (int e = 0; e < 4; ++e) {
        _Float16 hi = (_Float16)vv[e];
        float lo = vv[e] - (float)hi;
        h[e] = hi; l[e] = (_Float16)lo;
        acc += vv[e] * vv[e] + 2.0f * EPS_ * vv[e];
    }
    *(v4h*)(xh + (size_t)b * D_ + t * 4) = h;
    *(v4h*)(xl + (size_t)b * D_ + t * 4) = l;
    for (int off = 32; off; off >>= 1) acc += __shfl_down(acc, off, 64);
    __shared__ float s[4];
    if ((t & 63) == 0) s[t >> 6] = acc;
    __syncthreads();
    if (t == 0) rowTerm[b] = s[0] + s[1] + s[2] + s[3];
}

// ---------- convert+transpose W -> Wth,Wtl [m][d] + colTerm ----------
__global__ void wconv(const float* __restrict__ W,
                      _Float16* __restrict__ wth, _Float16* __restrict__ wtl,
                      float* __restrict__ colTerm) {
    __shared__ float tile[64][65];
    const int t = threadIdx.x;
    const int m0 = blockIdx.x * 64;
    const int d0 = blockIdx.y * 64;
    const int dloc = t >> 4, mq = (t & 15) * 4;
    #pragma unroll
    for (int s = 0; s < 4; ++s) {
        float4 v = *(const float4*)(W + (size_t)(d0 + dloc + 16 * s) * M_ + m0 + mq);
        tile[dloc + 16 * s][mq + 0] = v.x;
        tile[dloc + 16 * s][mq + 1] = v.y;
        tile[dloc + 16 * s][mq + 2] = v.z;
        tile[dloc + 16 * s][mq + 3] = v.w;
    }
    __syncthreads();
    const int dc = (t & 7) * 8;
    #pragma unroll
    for (int p = 0; p < 2; ++p) {
        int mloc = (t >> 3) + 32 * p;
        v8h h, l;
        float acc = 0.f;
        #pragma unroll
        for (int e = 0; e < 8; ++e) {
            float v = tile[dc + e][mloc];
            _Float16 hi = (_Float16)v;
            float lo = v - (float)hi;
            h[e] = hi; l[e] = (_Float16)lo;
            acc += v * v - 2.0f * EPS_ * v;
        }
        *(v8h*)(wth + (size_t)(m0 + mloc) * D_ + d0 + dc) = h;
        *(v8h*)(wtl + (size_t)(m0 + mloc) * D_ + d0 + dc) = l;
        acc += __shfl_down(acc, 4, 8);
        acc += __shfl_down(acc, 2, 8);
        acc += __shfl_down(acc, 1, 8);
        if ((t & 7) == 0) atomicAdd(&colTerm[m0 + mloc], acc);
    }
}

// ---------- main MFMA distance GEMM + argmin ----------
// 128x128 tile, 4 waves (2x2 of 64x64), BK=32, 32x32x16 f16 MFMA.
// LDS chunk (row m, 16B-chunk c) stored at slot m*4 + (c ^ (m&3)).
__global__ __launch_bounds__(256, 2) void som_mfma(
    const _Float16* __restrict__ xh, const _Float16* __restrict__ xl,
    const _Float16* __restrict__ wth, const _Float16* __restrict__ wtl,
    const float* __restrict__ rowTerm, const float* __restrict__ colTerm,
    unsigned long long* __restrict__ keys)
{
    __shared__ __align__(16) _Float16 smem[16384];  // 32 KB: Ah|Al|Bh|Bl
    _Float16* Ah = smem;
    _Float16* Al = smem + 4096;
    _Float16* Bh = smem + 8192;
    _Float16* Bl = smem + 12288;

    const int t  = threadIdx.x;
    const int rb = blockIdx.y * 128;
    const int cb = blockIdx.x * 128;
    const int L  = t & 63, w = t >> 6;
    const int wro = (w >> 1) * 64, wco = (w & 1) * 64;
    const int l31 = L & 31, q = L >> 5;

    // staging: LDS slot u holds (row u>>2, global chunk (u&3)^((u>>2)&3))
    const int m1 = t >> 2;
    const int c1 = (t & 3) ^ (m1 & 3);
    const size_t aoff1 = (size_t)(rb + m1) * 2048 + c1 * 16;
    const size_t aoff2 = aoff1 + 64ull * 2048;  // rows +64, same chunk swizzle
    const size_t boff1 = (size_t)(cb + m1) * 2048 + c1 * 16;
    const size_t boff2 = boff1 + 64ull * 2048;
    const int lds1 = (t & 192) * 16;          // wave-uniform base, lane scatter x16
    const int lds2 = lds1 + 4096;
    const char* pxh = (const char*)xh;
    const char* pxl = (const char*)xl;
    const char* pwh = (const char*)wth;
    const char* pwl = (const char*)wtl;

    v16f acc[2][2];
    #pragma unroll
    for (int i = 0; i < 2; ++i)
        #pragma unroll
        for (int j = 0; j < 2; ++j)
            #pragma unroll
            for (int r = 0; r < 16; ++r) acc[i][j][r] = 0.f;

    // fragment LDS indices (f16 units), de-swizzled
    int ia[2][2], ib[2][2];
    #pragma unroll
    for (int ti = 0; ti < 2; ++ti) {
        int mA = wro + ti * 32 + l31;
        int mB = wco + ti * 32 + l31;
        #pragma unroll
        for (int h = 0; h < 2; ++h) {
            int ch = h * 2 + q;
            ia[ti][h] = (mA * 4 + (ch ^ (mA & 3))) * 8;
            ib[ti][h] = (mB * 4 + (ch ^ (mB & 3))) * 8;
        }
    }

    for (int kb = 0; kb < 2048; kb += 64) {  // 64 B = BK (32 f16)
        __syncthreads();
        GLDS16(pxh + aoff1 + kb, (char*)Ah + lds1);
        GLDS16(pxh + aoff2 + kb, (char*)Ah + lds2);
        GLDS16(pxl + aoff1 + kb, (char*)Al + lds1);
        GLDS16(pxl + aoff2 + kb, (char*)Al + lds2);
        GLDS16(pwh + boff1 + kb, (char*)Bh + lds1);
        GLDS16(pwh + boff2 + kb, (char*)Bh + lds2);
        GLDS16(pwl + boff1 + kb, (char*)Bl + lds1);
        GLDS16(pwl + boff2 + kb, (char*)Bl + lds2);
        __syncthreads();

        v8h fah[2][2], fal[2][2], fbh[2][2], fbl[2][2];
        #pragma unroll
        for (int ti = 0; ti < 2; ++ti)
            #pragma unroll
            for (int h = 0; h < 2; ++h) {
                fah[ti][h] = *(const v8h*)(Ah + ia[ti][h]);
                fal[ti][h] = *(const v8h*)(Al + ia[ti][h]);
                fbh[ti][h] = *(const v8h*)(Bh + ib[ti][h]);
                fbl[ti][h] = *(const v8h*)(Bl + ib[ti][h]);
            }
        #pragma unroll
        for (int ti = 0; ti < 2; ++ti)
            #pragma unroll
            for (int tj = 0; tj < 2; ++tj)
                #pragma unroll
                for (int h = 0; h < 2; ++h) {
                    acc[ti][tj] = __builtin_amdgcn_mfma_f32_32x32x16_f16(
                        fah[ti][h], fbh[tj][h], acc[ti][tj], 0, 0, 0);
                    acc[ti][tj] = __builtin_amdgcn_mfma_f32_32x32x16_f16(
                        fah[ti][h], fbl[tj][h], acc[ti][tj], 0, 0, 0);
                    acc[ti][tj] = __builtin_amdgcn_mfma_f32_32x32x16_f16(
                        fal[ti][h], fbh[tj][h], acc[ti][tj], 0, 0, 0);
                }
    }

    // epilogue: 32x32 C/D layout col=lane&31, row=(reg&3)+8*(reg>>2)+4*(lane>>5)
    float cT[2];
    #pragma unroll
    for (int tj = 0; tj < 2; ++tj) cT[tj] = colTerm[cb + wco + tj * 32 + l31];
    const float de2 = (float)D_ * EPS_ * EPS_;
    #pragma unroll
    for (int ti = 0; ti < 2; ++ti) {
        #pragma unroll
        for (int reg = 0; reg < 16; ++reg) {
            int row_g = rb + wro + ti * 32 + (reg & 3) + 8 * (reg >> 2) + 4 * q;
            float rt = rowTerm[row_g];
            unsigned long long best = ~0ull;
            #pragma unroll
            for (int tj = 0; tj < 2; ++tj) {
                float sq = rt + cT[tj] - 2.0f * acc[ti][tj][reg] + de2;
                sq = fmaxf(sq, 0.0f);
                float dist = sqrtf(sq);
                unsigned long long key =
                    ((unsigned long long)__float_as_uint(dist) << 32) |
                    (unsigned int)(cb + wco + tj * 32 + l31);
                best = umin64(best, key);
            }
            #pragma unroll
            for (int m = 1; m <= 16; m <<= 1) {
                unsigned long long o =
                    (unsigned long long)__shfl_xor((long long)best, m, 64);
                best = umin64(best, o);
            }
            if (l31 == 0) atomicMin(&keys[row_g], best);
        }
    }
}

// ---------- fallback fp32 path (used only if ws too small) ----------
__global__ void row_stats(const float* __restrict__ x, float* __restrict__ rowTerm) {
    int b = blockIdx.x;
    const float* xr = x + (size_t)b * D_;
    int t = threadIdx.x;
    float acc = 0.f;
    for (int i = t; i < D_; i += 256) {
        float v = xr[i];
        acc += v * v + 2.0f * EPS_ * v;
    }
    for (int off = 32; off; off >>= 1) acc += __shfl_down(acc, off, 64);
    __shared__ float s[4];
    if ((t & 63) == 0) s[t >> 6] = acc;
    __syncthreads();
    if (t == 0) rowTerm[b] = s[0] + s[1] + s[2] + s[3];
}

__global__ void col_stats(const float* __restrict__ w, float* __restrict__ colTerm) {
    int m = blockIdx.x * 256 + threadIdx.x;
    int d0 = blockIdx.y * 64;
    const float* p = w + (size_t)d0 * M_ + m;
    float acc = 0.f;
    #pragma unroll 8
    for (int d = 0; d < 64; ++d) {
        float v = p[(size_t)d * M_];
        acc += v * v - 2.0f * EPS_ * v;
    }
    atomicAdd(&colTerm[m], acc);
}

__global__ __launch_bounds__(256, 2) void som_gemm(
    const float* __restrict__ A, const float* __restrict__ Wt,
    const float* __restrict__ rowTerm, const float* __restrict__ colTerm,
    unsigned long long* __restrict__ keys)
{
    __shared__ float As[8][128];
    __shared__ float Bs[8][128];
    const int t  = threadIdx.x;
    const int rb = blockIdx.y * 128;
    const int cb = blockIdx.x * 128;
    const int tx = t & 15;
    const int ty = t >> 4;
    float acc[8][8];
    #pragma unroll
    for (int i = 0; i < 8; ++i)
        #pragma unroll
        for (int j = 0; j < 8; ++j) acc[i][j] = 0.f;
    const int la_row = t >> 1, la_k = (t & 1) * 4;
    const int lb_k = t >> 5, lb_n = (t & 31) * 4;
    const float* Aptr = A + (size_t)(rb + la_row) * D_ + la_k;
    const float* Bptr = Wt + (size_t)lb_k * M_ + cb + lb_n;
    for (int k0 = 0; k0 < D_; k0 += 8) {
        float4 av = *(const float4*)(Aptr + k0);
        float4 bv = *(const float4*)(Bptr + (size_t)k0 * M_);
        __syncthreads();
        As[la_k + 0][la_row] = av.x;
        As[la_k + 1][la_row] = av.y;
        As[la_k + 2][la_row] = av.z;
        As[la_k + 3][la_row] = av.w;
        *(float4*)&Bs[lb_k][lb_n] = bv;
        __syncthreads();
        #pragma unroll
        for (int k = 0; k < 8; ++k) {
            float a[8], b[8];
            #pragma unroll
            for (int i = 0; i < 8; ++i) a[i] = As[k][ty * 8 + i];
            #pragma unroll
            for (int j = 0; j < 8; ++j) b[j] = Bs[k][tx * 8 + j];
            #pragma unroll
            for (int i = 0; i < 8; ++i)
                #pragma unroll
                for (int j = 0; j < 8; ++j) acc[i][j] += a[i] * b[j];
        }
    }
    float rT[8], cT[8];
    #pragma unroll
    for (int i = 0; i < 8; ++i) rT[i] = rowTerm[rb + ty * 8 + i];
    #pragma unroll
    for (int j = 0; j < 8; ++j) cT[j] = colTerm[cb + tx * 8 + j];
    const float de2 = (float)D_ * EPS_ * EPS_;
    #pragma unroll
    for (int i = 0; i < 8; ++i) {
        unsigned long long best = ~0ull;
        #pragma unroll
        for (int j = 0; j < 8; ++j) {
            float sq = rT[i] + cT[j] - 2.0f * acc[i][j] + de2;
            sq = fmaxf(sq, 0.0f);
            float dist = sqrtf(sq);
            unsigned long long key =
                ((unsigned long long)__float_as_uint(dist) << 32) |
                (unsigned int)(cb + tx * 8 + j);
            best = umin64(best, key);
        }
        #pragma unroll
        for (int msk = 1; msk <= 8; msk <<= 1) {
            unsigned long long o = __shfl_xor((long long)best, msk, 64);
            best = umin64(best, (unsigned long long)o);
        }
        if (tx == 0) atomicMin(&keys[rb + ty * 8 + i], best);
    }
}

// ---------- finalize: 8 blocks of 256 rows ----------
__global__ void finalize(const unsigned long long* __restrict__ keys,
                         const float* __restrict__ loc,
                         float* __restrict__ out)
{
    int t = threadIdx.x;
    int r = blockIdx.x * 256 + t;
    unsigned long long k = keys[r];
    unsigned int idx = (unsigned int)(k & 0xFFFFFFFFu);
    float dist = __uint_as_float((unsigned int)(k >> 32));
    out[r] = (float)idx;
    out[B_ + 2 * r]     = loc[2 * idx];
    out[B_ + 2 * r + 1] = loc[2 * idx + 1];
    float sum = dist;
    for (int off = 32; off; off >>= 1) sum += __shfl_down(sum, off, 64);
    __shared__ float s[4];
    if ((t & 63) == 0) s[t >> 6] = sum;
    __syncthreads();
    if (t == 0) atomicAdd(&out[3 * B_], (s[0] + s[1] + s[2] + s[3]) / (float)B_);
}

extern "C" void kernel_launch(void* const* d_in, const int* in_sizes, int n_in,
                              void* d_out, int out_size, void* d_ws, size_t ws_size,
                              hipStream_t stream)
{
    const float* x   = (const float*)d_in[0];
    const float* w   = (const float*)d_in[1];
    const float* loc = (const float*)d_in[2];
    float* out = (float*)d_out;

    char* ws = (char*)d_ws;
    unsigned long long* keys = (unsigned long long*)ws;   // 16 KB
    float* rowTerm = (float*)(ws + (16 << 10));           //  8 KB
    float* colTerm = (float*)(ws + (24 << 10));           // 64 KB
    _Float16* xh  = (_Float16*)(ws + (1ull << 20));       //  4 MB
    _Float16* xl  = (_Float16*)(ws + (5ull << 20));       //  4 MB
    _Float16* wth = (_Float16*)(ws + (9ull << 20));       // 32 MB
    _Float16* wtl = (_Float16*)(ws + (41ull << 20));      // 32 MB
    const size_t NEED = 73ull << 20;

    hipMemsetAsync(keys, 0xFF, B_ * sizeof(unsigned long long), stream);
    hipMemsetAsync(colTerm, 0, M_ * sizeof(float), stream);
    hipMemsetAsync(out + 3 * B_, 0, sizeof(float), stream);

    if (ws_size >= NEED) {
        xconv<<<B_, 256, 0, stream>>>(x, xh, xl, rowTerm);
        wconv<<<dim3(M_ / 64, D_ / 64), 256, 0, stream>>>(w, wth, wtl, colTerm);
        som_mfma<<<dim3(M_ / 128, B_ / 128), 256, 0, stream>>>(
            xh, xl, wth, wtl, rowTerm, colTerm, keys);
    } else {
        row_stats<<<B_, 256, 0, stream>>>(x, rowTerm);
        col_stats<<<dim3(M_ / 256, D_ / 64), 256, 0, stream>>>(w, colTerm);
        som_gemm<<<dim3(M_ / 128, B_ / 128), 256, 0, stream>>>(
            x, w, rowTerm, colTerm, keys);
    }
    finalize<<<8, 256, 0, stream>>>(keys, loc, out);
}